// Round 12
// baseline (315.134 us; speedup 1.0000x reference)
//
#include <hip/hip_runtime.h>

#define N 12288
#define M 24576            // keys (t_j) + queries (-s_i)
#define DIN 128
#define DOUT 64
#define NBIN 8192
#define BSHIFT 19          // 32 - log2(NBIN)
#define NCHUNK 384         // M / 64
#define NBLK 256
#define NTHR 256

// monotone float -> ordered u32 (order-preserving bit transform)
__device__ __forceinline__ unsigned f_ord(float x) {
    unsigned b = __float_as_uint(x);
    return (b & 0x80000000u) ? ~b : (b | 0x80000000u);
}
__device__ __forceinline__ float ord_f(unsigned u) {
    unsigned b = (u & 0x80000000u) ? (u & 0x7FFFFFFFu) : ~u;
    return __uint_as_float(b);
}
__device__ __forceinline__ int t_bin(float x) { return (int)(f_ord(x) >> BSHIFT); }

struct Args {
    const float *h, *W, *a;
    unsigned *cnt;                  // barrier counter (memset 0 pre-launch)
    int *hist, *binoff;             // memset 0 pre-launch
    float *tblkmax, *Wh;
    unsigned long long *vals64;     // (ordered(val)<<32)|pi — unique total order
    float *tfin; int *idfin;
    float2 *VU, *sc;                // per-chunk column/scalar sums {v,u}
    float *out;
};

union SMem {
    struct { float4 Ws4[2048]; float4 hs4[1536]; } a;          // 56 KB
    struct { int binstart[NBIN + 1]; int parts[192]; int wtot[4]; } cd;
};

// Custom grid barrier: release-add, acquire-spin. Monotonic counter, no reset.
// Cooperative launch guarantees co-residency of all 256 blocks.
__device__ __forceinline__ void gbar(unsigned* cnt, unsigned target) {
    __syncthreads();
    if (threadIdx.x == 0) {
        __threadfence();   // release: push this block's writes (L2 wb)
        __hip_atomic_fetch_add(cnt, 1u, __ATOMIC_RELEASE, __HIP_MEMORY_SCOPE_AGENT);
        while (__hip_atomic_load(cnt, __ATOMIC_ACQUIRE, __HIP_MEMORY_SCOPE_AGENT) < target)
            __builtin_amdgcn_s_sleep(1);
        // acquire-load above invalidates this CU's L1 / XCD L2
    }
    __syncthreads();
}

__global__ __launch_bounds__(NTHR) void gat_fused(Args A) {
    __shared__ SMem sm;
    __shared__ float wmaxs[4];
    int tid = threadIdx.x, wave = tid >> 6, lane = tid & 63, blk = blockIdx.x;
    int c0 = lane & 15, rq = lane >> 4;

    // ========== Phase A: GEMM (48 rows/block) + own-value histogram ========
    float tvr[3], svr[3];
    {
        const float4* W4 = (const float4*)A.W;
        #pragma unroll
        for (int e = tid; e < 2048; e += NTHR) sm.a.Ws4[e] = W4[e];
        int row0 = blk * 48;
        const float4* h4 = (const float4*)(A.h + (size_t)row0 * DIN);
        #pragma unroll
        for (int e = tid; e < 1536; e += NTHR) sm.a.hs4[e] = h4[e];
        __syncthreads();
        int rbase = wave * 12 + rq * 3;        // 4 waves x 12 rows = 48
        float4 acc[3];
        #pragma unroll
        for (int rr = 0; rr < 3; ++rr) acc[rr] = make_float4(0.f, 0.f, 0.f, 0.f);
        #pragma unroll 2
        for (int kk = 0; kk < 32; ++kk) {
            float4 w0 = sm.a.Ws4[(4 * kk + 0) * 16 + c0];
            float4 w1 = sm.a.Ws4[(4 * kk + 1) * 16 + c0];
            float4 w2 = sm.a.Ws4[(4 * kk + 2) * 16 + c0];
            float4 w3 = sm.a.Ws4[(4 * kk + 3) * 16 + c0];
            #pragma unroll
            for (int rr = 0; rr < 3; ++rr) {
                float4 hv = sm.a.hs4[(rbase + rr) * 32 + kk];
                acc[rr].x = fmaf(hv.x, w0.x, acc[rr].x);
                acc[rr].y = fmaf(hv.x, w0.y, acc[rr].y);
                acc[rr].z = fmaf(hv.x, w0.z, acc[rr].z);
                acc[rr].w = fmaf(hv.x, w0.w, acc[rr].w);
                acc[rr].x = fmaf(hv.y, w1.x, acc[rr].x);
                acc[rr].y = fmaf(hv.y, w1.y, acc[rr].y);
                acc[rr].z = fmaf(hv.y, w1.z, acc[rr].z);
                acc[rr].w = fmaf(hv.y, w1.w, acc[rr].w);
                acc[rr].x = fmaf(hv.z, w2.x, acc[rr].x);
                acc[rr].y = fmaf(hv.z, w2.y, acc[rr].y);
                acc[rr].z = fmaf(hv.z, w2.z, acc[rr].z);
                acc[rr].w = fmaf(hv.z, w2.w, acc[rr].w);
                acc[rr].x = fmaf(hv.w, w3.x, acc[rr].x);
                acc[rr].y = fmaf(hv.w, w3.y, acc[rr].y);
                acc[rr].z = fmaf(hv.w, w3.z, acc[rr].z);
                acc[rr].w = fmaf(hv.w, w3.w, acc[rr].w);
            }
        }
        float4 a1 = ((const float4*)A.a)[c0];
        float4 a2 = ((const float4*)A.a)[16 + c0];
        float tmax = -3.4e38f;
        #pragma unroll
        for (int rr = 0; rr < 3; ++rr) {
            int row = row0 + rbase + rr;
            ((float4*)A.Wh)[(size_t)row * 16 + c0] = acc[rr];
            float sv = acc[rr].x * a1.x + acc[rr].y * a1.y + acc[rr].z * a1.z + acc[rr].w * a1.w;
            float tv = acc[rr].x * a2.x + acc[rr].y * a2.y + acc[rr].z * a2.z + acc[rr].w * a2.w;
            #pragma unroll
            for (int off = 8; off; off >>= 1) {     // allreduce over 16-group
                sv += __shfl_xor(sv, off, 64);
                tv += __shfl_xor(tv, off, 64);
            }
            tvr[rr] = tv; svr[rr] = sv;
            tmax = fmaxf(tmax, tv);
        }
        #pragma unroll
        for (int off = 1; off < 64; off <<= 1) tmax = fmaxf(tmax, __shfl_xor(tmax, off, 64));
        if (lane == 0) wmaxs[wave] = tmax;
        __syncthreads();
        if (tid == 0)
            A.tblkmax[blk] = fmaxf(fmaxf(wmaxs[0], wmaxs[1]), fmaxf(wmaxs[2], wmaxs[3]));
        if (c0 == 0) {                              // 16 threads x 6 hist adds
            #pragma unroll
            for (int rr = 0; rr < 3; ++rr) {
                atomicAdd(&A.hist[t_bin(tvr[rr])], 1);
                atomicAdd(&A.hist[t_bin(-svr[rr])], 1);
            }
        }
    }
    gbar(A.cnt, 1 * NBLK);

    // ========== Phase CD: redundant LDS scan of hist + register scatter ====
    {
        const int4* hg = (const int4*)A.hist;
        int4 tmp[8];
        int s = 0;
        #pragma unroll
        for (int g = 0; g < 8; ++g) {               // 32 bins/thread
            tmp[g] = hg[tid * 8 + g];
            s += tmp[g].x + tmp[g].y + tmp[g].z + tmp[g].w;
        }
        int inc = s;
        #pragma unroll
        for (int off = 1; off < 64; off <<= 1) {
            int nb = __shfl_up(inc, off, 64);
            if (lane >= off) inc += nb;
        }
        if (lane == 63) sm.cd.wtot[wave] = inc;
        __syncthreads();
        int wbase = 0;
        #pragma unroll
        for (int w = 0; w < 4; ++w) wbase += (w < wave) ? sm.cd.wtot[w] : 0;
        int run = wbase + inc - s;
        int base = tid * 32;
        #pragma unroll
        for (int g = 0; g < 8; ++g) {
            sm.cd.binstart[base + 4 * g + 0] = run; run += tmp[g].x;
            sm.cd.binstart[base + 4 * g + 1] = run; run += tmp[g].y;
            sm.cd.binstart[base + 4 * g + 2] = run; run += tmp[g].z;
            sm.cd.binstart[base + 4 * g + 3] = run; run += tmp[g].w;
        }
        if (tid == 255) sm.cd.binstart[NBIN] = M;
        __syncthreads();
        if (c0 == 0) {                              // scatter own 96 items
            int row0 = blk * 48 + wave * 12 + rq * 3;
            #pragma unroll
            for (int rr = 0; rr < 3; ++rr) {
                float tv = tvr[rr];
                int bt = t_bin(tv);
                int pos = sm.cd.binstart[bt] + atomicAdd(&A.binoff[bt], 1);
                A.vals64[pos] = ((unsigned long long)f_ord(tv) << 32)
                              | (unsigned)(row0 + rr + N);
                float qv = -svr[rr];
                int bq = t_bin(qv);
                pos = sm.cd.binstart[bq] + atomicAdd(&A.binoff[bq], 1);
                A.vals64[pos] = ((unsigned long long)f_ord(qv) << 32)
                              | (unsigned)(row0 + rr);
            }
        }
    }
    gbar(A.cnt, 2 * NBLK);

    // ========== Phase E: exact in-bin rank (2 subs/position, binstart in LDS)
    {
        int li = tid % 96, sub = tid / 96;          // sub 2 (tid>=192) idle
        if (sub < 2) {
            int p = blk * 96 + li;
            unsigned long long kp = A.vals64[p];
            int b = (int)(kp >> (32 + BSHIFT));
            int lo = sm.cd.binstart[b], hi = sm.cd.binstart[b + 1];
            int mid = lo + ((hi - lo + 1) >> 1);
            int qlo = sub ? mid : lo, qhi = sub ? hi : mid;
            int cnt = 0, q = qlo;
            while (q < qhi && (q & 3)) cnt += (int)(A.vals64[q++] < kp);
            int bend = q + ((qhi - q) & ~3);
            #pragma unroll 2
            for (; q < bend; q += 4) {
                ulonglong2 u0 = *(const ulonglong2*)&A.vals64[q];
                ulonglong2 u1 = *(const ulonglong2*)&A.vals64[q + 2];
                cnt += (int)(u0.x < kp) + (int)(u0.y < kp)
                     + (int)(u1.x < kp) + (int)(u1.y < kp);
            }
            while (q < qhi) cnt += (int)(A.vals64[q++] < kp);
            sm.cd.parts[sub * 96 + li] = cnt;
        }
        __syncthreads();
        if (tid < 96) {
            int p = blk * 96 + tid;
            unsigned long long kp = A.vals64[p];
            int b = (int)(kp >> (32 + BSHIFT));
            int lo = sm.cd.binstart[b];
            int tot = sm.cd.parts[tid] + sm.cd.parts[96 + tid];
            unsigned pi = (unsigned)(kp & 0xffffffffu);
            A.tfin[lo + tot] = ord_f((unsigned)(kp >> 32));
            A.idfin[lo + tot] = (pi >= N) ? (int)(pi - N) : (int)(pi + N);
        }
    }
    gbar(A.cnt, 3 * NBLK);

    // redundant per-wave T = max(t) from per-block maxima (1 KB, L2-hot)
    float T;
    {
        float m = fmaxf(fmaxf(A.tblkmax[lane], A.tblkmax[64 + lane]),
                        fmaxf(A.tblkmax[128 + lane], A.tblkmax[192 + lane]));
        #pragma unroll
        for (int off = 1; off < 64; off <<= 1) m = fmaxf(m, __shfl_xor(m, off, 64));
        T = m;
    }

    // ========== Phase F: per-chunk key-sums (chunk = blk + 256*wave) ========
    if (wave < 2) {
        int c = blk + 256 * wave;
        if (c < NCHUNK) {
            float myval = A.tfin[c * 64 + lane];
            int myid = A.idfin[c * 64 + lane];
            float x[64];
            #pragma unroll
            for (int k = 0; k < 64; ++k) {
                int uid = __shfl(myid, k, 64);
                x[k] = (uid < N) ? A.Wh[(size_t)uid * DOUT + lane] : 0.f;
            }
            float av = 0.f, au = 0.f, svs = 0.f, sus = 0.f;
            #pragma unroll
            for (int k = 0; k < 64; ++k) {
                int uid = __shfl(myid, k, 64);
                if (uid < N) {
                    float uval = __shfl(myval, k, 64);
                    float wv = expf(0.2f * (uval - T));
                    float w2 = wv * wv, w4 = w2 * w2;
                    float wu = w4 * wv;             // exp(uval-T) = wv^5
                    av = fmaf(wv, x[k], av); au = fmaf(wu, x[k], au);
                    svs += wv; sus += wu;
                }
            }
            A.VU[c * 64 + lane] = make_float2(av, au);
            if (lane == 0) A.sc[c] = make_float2(svs, sus);
        }
    }
    gbar(A.cnt, 4 * NBLK);

    // ========== Phase H: bases (predicated coalesced pass) + sweep ==========
    if (wave < 2) {
        int c = blk + 256 * wave;
        if (c < NCHUNK) {
            float bv = 0.f, bu = 0.f, bvs = 0.f, bus = 0.f, tu = 0.f, tus = 0.f;
            #pragma unroll 4
            for (int cp = 0; cp < NCHUNK; ++cp) {
                float2 vu = A.VU[cp * 64 + lane];   // coalesced, L2-hot
                float2 s2 = A.sc[cp];
                bool below = cp < c;
                bv += below ? vu.x : 0.f; bu += below ? vu.y : 0.f;
                bvs += below ? s2.x : 0.f; bus += below ? s2.y : 0.f;
                tu += vu.y; tus += s2.y;
            }
            float myval = A.tfin[c * 64 + lane];
            int myid = A.idfin[c * 64 + lane];
            float x[64];
            #pragma unroll
            for (int k = 0; k < 64; ++k) {
                int uid = __shfl(myid, k, 64);
                x[k] = (uid < N) ? A.Wh[(size_t)uid * DOUT + lane] : 0.f;
            }
            float rv = bv, ru = bu, rvs = bvs, rus = bus;
            #pragma unroll
            for (int k = 0; k < 64; ++k) {
                float uval = __shfl(myval, k, 64);
                int uid = __shfl(myid, k, 64);
                if (uid < N) {                      // key: advance running sums
                    float wv = expf(0.2f * (uval - T));
                    float w2 = wv * wv, w4 = w2 * w2;
                    float wu = w4 * wv;
                    rv = fmaf(wv, x[k], rv); ru = fmaf(wu, x[k], ru);
                    rvs += wv; rus += wu;
                } else {                            // query: emit output row
                    int i = uid - N;
                    float si = -uval;
                    float xx = si + T;
                    float mm = fmaxf(xx, 0.2f * xx);
                    float cp_ = expf(xx - mm);
                    float cn_ = expf(0.2f * xx - mm);
                    float num = cn_ * rv + cp_ * (tu - ru);
                    float den = cn_ * rvs + cp_ * (tus - rus);
                    float r = num / den;
                    A.out[(size_t)i * DOUT + lane] = r > 0.f ? r : expm1f(r);
                }
            }
        }
    }
}

extern "C" void kernel_launch(void* const* d_in, const int* in_sizes, int n_in,
                              void* d_out, int out_size, void* d_ws, size_t ws_size,
                              hipStream_t stream) {
    float* ws = (float*)d_ws;
    size_t o = 0;
    Args A;
    A.h = (const float*)d_in[0];
    A.W = (const float*)d_in[1];
    A.a = (const float*)d_in[2];
    A.out = (float*)d_out;
    A.cnt     = (unsigned*)(ws + o); o += 16;       // 64 B header
    A.hist    = (int*)(ws + o); o += NBIN;
    A.binoff  = (int*)(ws + o); o += NBIN;
    A.tblkmax = ws + o; o += NBLK;
    A.Wh      = ws + o; o += (size_t)N * DOUT;
    A.vals64  = (unsigned long long*)(ws + o); o += 2 * (size_t)M;
    A.tfin    = ws + o; o += M;
    A.idfin   = (int*)(ws + o); o += M;
    A.VU      = (float2*)(ws + o); o += 2 * (size_t)NCHUNK * DOUT;
    A.sc      = (float2*)(ws + o); o += 2 * NCHUNK;
    // ~3.7 MB total

    // zero barrier counter + hist + binoff (contiguous at ws start)
    hipMemsetAsync(d_ws, 0, (16 + 2 * NBIN) * sizeof(float), stream);
    void* kargs[] = { (void*)&A };
    hipLaunchCooperativeKernel((void*)gat_fused, dim3(NBLK), dim3(NTHR),
                               kargs, 0, stream);
}

// Round 13
// 133.733 us; speedup vs baseline: 2.3564x; 2.3564x over previous
//
#include <hip/hip_runtime.h>

#define N 12288
#define M (2 * N)          // keys (t_j) + queries (-s_i)
#define DIN 128
#define DOUT 64
#define NBIN 8192
#define BSHIFT 19          // 32 - log2(NBIN)
#define NCHUNK 384         // M / 64

// monotone float -> ordered u32 (order-preserving bit transform)
__device__ __forceinline__ unsigned f_ord(float x) {
    unsigned b = __float_as_uint(x);
    return (b & 0x80000000u) ? ~b : (b | 0x80000000u);
}
__device__ __forceinline__ float ord_f(unsigned u) {
    unsigned b = (u & 0x80000000u) ? (u & 0x7FFFFFFFu) : ~u;
    return __uint_as_float(b);
}
__device__ __forceinline__ int t_bin(float x) { return (int)(f_ord(x) >> BSHIFT); }

struct Args {
    const float *h, *W, *a;
    float *Wh, *s, *t, *tblkmax, *Thdr;
    unsigned long long *vals64;     // (ordered(val)<<32)|pi — unique total order
    float *tfin;
    int *idfin, *binstart;
    float2 *VU, *sc;                // per-chunk column/scalar sums {v,u}
    float *out;
};

// ---------- K1: Wh = h@W, s, t, per-block max(t) (384 blocks x 128) ---------
__global__ __launch_bounds__(128) void k1_gemm(Args A) {
    __shared__ float4 sm4[3072];               // 48 KB: W 32K + h-tile 16K
    __shared__ float wmax[2];
    int tid = threadIdx.x, wave = tid >> 6, lane = tid & 63, blk = blockIdx.x;
    float4* Ws4 = sm4;                         // W[k][c4]  (2048)
    float4* hs4 = sm4 + 2048;                  // h[r][k4]  (1024: 32 rows)
    const float4* W4 = (const float4*)A.W;
    #pragma unroll
    for (int e = tid; e < 2048; e += 128) Ws4[e] = W4[e];
    int row0 = blk * 32;
    const float4* h4 = (const float4*)(A.h + (size_t)row0 * DIN);
    #pragma unroll
    for (int e = tid; e < 1024; e += 128) hs4[e] = h4[e];
    __syncthreads();
    int c0 = lane & 15, rq = lane >> 4;
    int rbase = wave * 16 + rq * 4;            // 2 waves cover 32 rows
    float4 acc[4];
    #pragma unroll
    for (int rr = 0; rr < 4; ++rr) acc[rr] = make_float4(0.f, 0.f, 0.f, 0.f);
    #pragma unroll 2
    for (int kk = 0; kk < 32; ++kk) {
        float4 w0 = Ws4[(4 * kk + 0) * 16 + c0];
        float4 w1 = Ws4[(4 * kk + 1) * 16 + c0];
        float4 w2 = Ws4[(4 * kk + 2) * 16 + c0];
        float4 w3 = Ws4[(4 * kk + 3) * 16 + c0];
        #pragma unroll
        for (int rr = 0; rr < 4; ++rr) {
            float4 hv = hs4[(rbase + rr) * 32 + kk];
            acc[rr].x = fmaf(hv.x, w0.x, acc[rr].x);
            acc[rr].y = fmaf(hv.x, w0.y, acc[rr].y);
            acc[rr].z = fmaf(hv.x, w0.z, acc[rr].z);
            acc[rr].w = fmaf(hv.x, w0.w, acc[rr].w);
            acc[rr].x = fmaf(hv.y, w1.x, acc[rr].x);
            acc[rr].y = fmaf(hv.y, w1.y, acc[rr].y);
            acc[rr].z = fmaf(hv.y, w1.z, acc[rr].z);
            acc[rr].w = fmaf(hv.y, w1.w, acc[rr].w);
            acc[rr].x = fmaf(hv.z, w2.x, acc[rr].x);
            acc[rr].y = fmaf(hv.z, w2.y, acc[rr].y);
            acc[rr].z = fmaf(hv.z, w2.z, acc[rr].z);
            acc[rr].w = fmaf(hv.z, w2.w, acc[rr].w);
            acc[rr].x = fmaf(hv.w, w3.x, acc[rr].x);
            acc[rr].y = fmaf(hv.w, w3.y, acc[rr].y);
            acc[rr].z = fmaf(hv.w, w3.z, acc[rr].z);
            acc[rr].w = fmaf(hv.w, w3.w, acc[rr].w);
        }
    }
    float4 a1 = ((const float4*)A.a)[c0];
    float4 a2 = ((const float4*)A.a)[16 + c0];
    float tmax = -3.4e38f;
    #pragma unroll
    for (int rr = 0; rr < 4; ++rr) {
        int row = row0 + rbase + rr;
        ((float4*)A.Wh)[(size_t)row * 16 + c0] = acc[rr];
        float sv = acc[rr].x * a1.x + acc[rr].y * a1.y + acc[rr].z * a1.z + acc[rr].w * a1.w;
        float tv = acc[rr].x * a2.x + acc[rr].y * a2.y + acc[rr].z * a2.z + acc[rr].w * a2.w;
        #pragma unroll
        for (int off = 8; off; off >>= 1) {     // reduce over 16-lane group
            sv += __shfl_xor(sv, off, 64);
            tv += __shfl_xor(tv, off, 64);
        }
        if (c0 == 0) { A.s[row] = sv; A.t[row] = tv; }
        tmax = fmaxf(tmax, tv);
    }
    tmax = fmaxf(tmax, __shfl_xor(tmax, 16, 64));
    tmax = fmaxf(tmax, __shfl_xor(tmax, 32, 64));
    if (lane == 0) wmax[wave] = tmax;
    __syncthreads();
    if (tid == 0) A.tblkmax[blk] = fmaxf(wmax[0], wmax[1]);
}

// ---------- K2: LDS hist + pre-hist + scan + T + packed-key scatter ----------
__global__ __launch_bounds__(1024) void k2_sort(Args A) {
    __shared__ int hist[NBIN];                  // 32 KB
    __shared__ int pre[NBIN];                   // 32 KB
    __shared__ int wtot[16];
    __shared__ float fmax_[16];
    int tid = threadIdx.x, lane = tid & 63, wave = tid >> 6, blk = blockIdx.x;
    #pragma unroll
    for (int e = tid; e < NBIN; e += 1024) { hist[e] = 0; pre[e] = 0; }
    __syncthreads();
    #pragma unroll 4
    for (int e = tid; e < M; e += 1024) {
        float v = (e < N) ? A.t[e] : -A.s[e - N];
        atomicAdd(&hist[t_bin(v)], 1);
    }
    int my0 = blk * 1024;
    #pragma unroll 4
    for (int e = tid; e < my0; e += 1024) {
        float v = (e < N) ? A.t[e] : -A.s[e - N];
        atomicAdd(&pre[t_bin(v)], 1);
    }
    __syncthreads();
    int b0 = tid * 8;
    int c8[8]; int sum = 0;
    #pragma unroll
    for (int g = 0; g < 8; ++g) { c8[g] = sum; sum += hist[b0 + g]; }
    int inc = sum;
    #pragma unroll
    for (int off = 1; off < 64; off <<= 1) {
        int nb = __shfl_up(inc, off, 64);
        if (lane >= off) inc += nb;
    }
    if (lane == 63) wtot[wave] = inc;
    __syncthreads();
    int wbase = 0;
    #pragma unroll
    for (int w = 0; w < 16; ++w) wbase += (w < wave) ? wtot[w] : 0;
    int tstart = wbase + inc - sum;
    #pragma unroll
    for (int g = 0; g < 8; ++g) {
        int bs = tstart + c8[g];
        hist[b0 + g] = bs;
        pre[b0 + g] += bs;
        A.binstart[b0 + g] = bs;                // benign duplicate across blocks
    }
    if (tid == 0 && blk == 0) A.binstart[NBIN] = M;
    float m = (tid < 384) ? A.tblkmax[tid] : -3.4e38f;
    #pragma unroll
    for (int off = 32; off; off >>= 1) m = fmaxf(m, __shfl_xor(m, off, 64));
    if (lane == 0) fmax_[wave] = m;
    __syncthreads();
    if (tid == 0) {
        float mm = fmax_[0];
        #pragma unroll
        for (int w = 1; w < 16; ++w) mm = fmaxf(mm, fmax_[w]);
        A.Thdr[0] = mm;
    }
    __syncthreads();
    {   // exactly one item per thread (slice == blockDim)
        int e = my0 + tid;
        float v = (e < N) ? A.t[e] : -A.s[e - N];
        int pi = (e < N) ? (e + N) : (e - N);   // queries sort before equal keys
        int pos = atomicAdd(&pre[t_bin(v)], 1);
        A.vals64[pos] = ((unsigned long long)f_ord(v) << 32) | (unsigned)pi;
    }
}

// ---------- K3: exact in-bin rank, 8 THREADS per position ----------
// 768 blocks x 256: item = blk*32 + (tid&31), sub = tid>>5 scans one eighth
// of the item's bin; partial counts combined via LDS.
__global__ __launch_bounds__(256) void k3_rank(Args A) {
    __shared__ int parts[256];
    int tid = threadIdx.x;
    int li = tid & 31, sub = tid >> 5;
    int p = blockIdx.x * 32 + li;
    unsigned long long kp = A.vals64[p];
    int b = (int)(kp >> (32 + BSHIFT));
    int lo = A.binstart[b], hi = A.binstart[b + 1];
    int len = hi - lo;
    int qlen = (len + 7) >> 3;
    int qlo = lo + sub * qlen;
    if (qlo > hi) qlo = hi;
    int qhi = qlo + qlen;
    if (qhi > hi) qhi = hi;
    int cnt = 0;
    int q = qlo;
    while (q < qhi && (q & 3)) cnt += (int)(A.vals64[q++] < kp);
    int bend = q + ((qhi - q) & ~3);
    #pragma unroll 2
    for (; q < bend; q += 4) {
        ulonglong2 u0 = *(const ulonglong2*)&A.vals64[q];
        ulonglong2 u1 = *(const ulonglong2*)&A.vals64[q + 2];
        cnt += (int)(u0.x < kp) + (int)(u0.y < kp)
             + (int)(u1.x < kp) + (int)(u1.y < kp);
    }
    while (q < qhi) cnt += (int)(A.vals64[q++] < kp);
    parts[sub * 32 + li] = cnt;
    __syncthreads();
    if (sub == 0) {
        int tot = 0;
        #pragma unroll
        for (int w = 0; w < 8; ++w) tot += parts[w * 32 + li];
        int pi = (int)(unsigned)(kp & 0xffffffffu);
        A.tfin[lo + tot] = ord_f((unsigned)(kp >> 32));
        A.idfin[lo + tot] = (pi >= N) ? (pi - N) : (pi + N);
    }
}

// ---------- K4: per-chunk (64 sorted items) key-sums (96 blocks x 256) ------
__global__ __launch_bounds__(256) void k4_sums(Args A) {
    int tid = threadIdx.x, wave = tid >> 6, lane = tid & 63;
    int c = blockIdx.x * 4 + wave;              // 384 chunks
    float T = A.Thdr[0];
    float myval = A.tfin[c * 64 + lane];
    int myid = A.idfin[c * 64 + lane];
    float x[64];
    #pragma unroll
    for (int k = 0; k < 64; ++k) {              // 64 independent gathers
        int uid = __shfl(myid, k, 64);
        x[k] = (uid < N) ? A.Wh[(size_t)uid * DOUT + lane] : 0.f;
    }
    float av = 0.f, au = 0.f, svs = 0.f, sus = 0.f;
    #pragma unroll
    for (int k = 0; k < 64; ++k) {
        int uid = __shfl(myid, k, 64);
        if (uid < N) {
            float uval = __shfl(myval, k, 64);
            float wv = expf(0.2f * (uval - T));
            float w2 = wv * wv, w4 = w2 * w2;
            float wu = w4 * wv;                 // exp(uval-T) = wv^5
            av = fmaf(wv, x[k], av); au = fmaf(wu, x[k], au);
            svs += wv; sus += wu;
        }
    }
    A.VU[c * 64 + lane] = make_float2(av, au);
    if (lane == 0) A.sc[c] = make_float2(svs, sus);
}

// ---------- K45: cooperative bases + sweep; queries emit output -------------
// 96 blocks x 256. Block handles chunks cbase..cbase+3 (cbase = blk*4).
// Wave w sums residue class cp≡w (mod 4) of the chunk records (fixed 96-trip
// loop -> pipelined independent loads); LDS-combine gives the shared prefix
// P(cbase) and U totals; wave w adds its <=3 marginal chunk records.
__global__ __launch_bounds__(256) void k45_apply(Args A) {
    __shared__ float2 pvu[4][64];   // per-wave partial base {V,U} per lane
    __shared__ float2 psc[4];       // per-wave partial base scalars {vs,us}
    __shared__ float  ptu[4][64];   // per-wave partial U-column totals
    __shared__ float  ptus[4];      // per-wave partial U-scalar totals
    int tid = threadIdx.x, wave = tid >> 6, lane = tid & 63;
    int cbase = blockIdx.x * 4;
    float T = A.Thdr[0];
    float bv = 0.f, bu = 0.f, bvs = 0.f, bus = 0.f, tu = 0.f, tus = 0.f;
    #pragma unroll 8
    for (int g = 0; g < NCHUNK / 4; ++g) {      // fixed 96 trips
        int cp = wave + 4 * g;
        float2 vu = A.VU[cp * 64 + lane];       // coalesced, L2-hot
        float2 s2 = A.sc[cp];
        bool below = cp < cbase;
        bv += below ? vu.x : 0.f; bu += below ? vu.y : 0.f;
        bvs += below ? s2.x : 0.f; bus += below ? s2.y : 0.f;
        tu += vu.y; tus += s2.y;
    }
    pvu[wave][lane] = make_float2(bv, bu);
    ptu[wave][lane] = tu;
    if (lane == 0) { psc[wave] = make_float2(bvs, bus); ptus[wave] = tus; }
    __syncthreads();
    float rv = 0.f, ru = 0.f, rvs = 0.f, rus = 0.f;
    tu = 0.f; tus = 0.f;
    #pragma unroll
    for (int w = 0; w < 4; ++w) {
        float2 q = pvu[w][lane];
        rv += q.x; ru += q.y;
        tu += ptu[w][lane];
        float2 qs = psc[w];
        rvs += qs.x; rus += qs.y;
        tus += ptus[w];
    }
    for (int j = 0; j < wave; ++j) {            // marginal chunks (<=3)
        float2 r = A.VU[(cbase + j) * 64 + lane];
        float2 s2 = A.sc[cbase + j];
        rv += r.x; ru += r.y; rvs += s2.x; rus += s2.y;
    }
    int c = cbase + wave;
    float myval = A.tfin[c * 64 + lane];
    int myid = A.idfin[c * 64 + lane];
    float x[64];
    #pragma unroll
    for (int k = 0; k < 64; ++k) {              // 64 independent gathers
        int uid = __shfl(myid, k, 64);
        x[k] = (uid < N) ? A.Wh[(size_t)uid * DOUT + lane] : 0.f;
    }
    #pragma unroll
    for (int k = 0; k < 64; ++k) {
        float uval = __shfl(myval, k, 64);
        int uid = __shfl(myid, k, 64);
        if (uid < N) {                          // key: advance running sums
            float wv = expf(0.2f * (uval - T));
            float w2 = wv * wv, w4 = w2 * w2;
            float wu = w4 * wv;                 // exp(uval-T)
            rv = fmaf(wv, x[k], rv); ru = fmaf(wu, x[k], ru);
            rvs += wv; rus += wu;
        } else {                                // query: emit output row
            int i = uid - N;
            float si = -uval;
            float xx = si + T;
            float mm = fmaxf(xx, 0.2f * xx);
            float cp_ = expf(xx - mm);
            float cn_ = expf(0.2f * xx - mm);
            float num = cn_ * rv + cp_ * (tu - ru);
            float den = cn_ * rvs + cp_ * (tus - rus);
            float r = num / den;
            A.out[(size_t)i * DOUT + lane] = r > 0.f ? r : expm1f(r);
        }
    }
}

extern "C" void kernel_launch(void* const* d_in, const int* in_sizes, int n_in,
                              void* d_out, int out_size, void* d_ws, size_t ws_size,
                              hipStream_t stream) {
    float* ws = (float*)d_ws;
    size_t o = 0;
    Args A;
    A.h = (const float*)d_in[0];
    A.W = (const float*)d_in[1];
    A.a = (const float*)d_in[2];
    A.out = (float*)d_out;
    A.Wh      = ws + o; o += (size_t)N * DOUT;
    A.s       = ws + o; o += N;
    A.t       = ws + o; o += N;
    A.tblkmax = ws + o; o += NCHUNK;            // 384 k1 blocks
    A.Thdr    = ws + o; o += 16;                // keeps o 16B-aligned
    A.vals64  = (unsigned long long*)(ws + o); o += 2 * (size_t)M;
    A.tfin    = ws + o; o += M;
    A.VU      = (float2*)(ws + o); o += 2 * (size_t)NCHUNK * DOUT;
    A.sc      = (float2*)(ws + o); o += 2 * NCHUNK;
    A.idfin    = (int*)(ws + o); o += M;
    A.binstart = (int*)(ws + o); o += NBIN + 1;
    // ~3.9 MB total; no initialization required

    k1_gemm  <<<N / 32, 128, 0, stream>>>(A);
    k2_sort  <<<24, 1024, 0, stream>>>(A);
    k3_rank  <<<M / 32, 256, 0, stream>>>(A);
    k4_sums  <<<NCHUNK / 4, 256, 0, stream>>>(A);
    k45_apply<<<NCHUNK / 4, 256, 0, stream>>>(A);
}